// Round 7
// baseline (86.671 us; speedup 1.0000x reference)
//
#include <hip/hip_runtime.h>
#include <hip/hip_bf16.h>

typedef __attribute__((ext_vector_type(8))) short short8;
typedef __attribute__((ext_vector_type(4))) float f32x4;
typedef unsigned short u16;
typedef unsigned int u32;

#define NROWS 8192
#define HALF  4096
#define DIM   256
#define TEMP_INV 2.0f   // 1/temperature
#define NBT 64                        // 8192/128 tiles per side
#define NBLK (NBT * (NBT + 1) / 2)    // 2080 triangular tiles
#define NSLAB 128                     // 64 tiles * 2 wave-halves

__device__ __forceinline__ u16 f2bf(float f) {
    union { float f; u32 i; } c; c.f = f;
    u32 lsb = (c.i >> 16) & 1;
    c.i += 0x7fffu + lsb;   // round-to-nearest-even
    return (u16)(c.i >> 16);
}

// ---------------- kernel 1: normalize rows, write bf16 ----------------------
__global__ __launch_bounds__(256) void normalize_k(const float* __restrict__ zi,
                                                   const float* __restrict__ zj,
                                                   u16* __restrict__ zn) {
    const int row  = blockIdx.x * 4 + (threadIdx.x >> 6);
    const int lane = threadIdx.x & 63;
    const float* src = (row < HALF) ? (zi + (size_t)row * DIM)
                                    : (zj + (size_t)(row - HALF) * DIM);
    float4 v = reinterpret_cast<const float4*>(src)[lane];
    float ss = v.x * v.x + v.y * v.y + v.z * v.z + v.w * v.w;
    #pragma unroll
    for (int m = 32; m; m >>= 1) ss += __shfl_xor(ss, m);
    const float inv = 1.0f / fmaxf(sqrtf(ss), 1e-8f);
    ushort4 o;
    o.x = f2bf(v.x * inv); o.y = f2bf(v.y * inv);
    o.z = f2bf(v.z * inv); o.w = f2bf(v.w * inv);
    reinterpret_cast<ushort4*>(zn + (size_t)row * DIM)[lane] = o;
}

// ---------------- kernel 2: LDS-free triangular GEMM + exp + slab sums ------
// No LDS, no barriers: each wave loads its MFMA fragments straight from
// global (zn is L2-resident). Lane l's 16B frag covers row (base + l&15),
// k = u*32 + (l>>4)*8; lanes {l, l+16, l+32, l+48} read one contiguous 64B
// line -> zero overfetch. 4 independent waves/block, compiler schedules the
// fully-unrolled K loop (reg double-buffer, counted vmcnt auto-inserted).
__global__ __launch_bounds__(256, 3) void gemm_exp_rowsum(const u16* __restrict__ zn,
                                                          float* __restrict__ slab,
                                                          float* __restrict__ pos) {
    // XCD-aware bijective swizzle (2080 = 8 * 260)
    const int b0 = blockIdx.x;
    const int b  = (b0 & 7) * (NBLK / 8) + (b0 >> 3);
    // Triangular decode: b -> (by, bx), by <= bx < 64
    int by = (int)((129.0f - sqrtf(129.0f * 129.0f - 8.0f * (float)b)) * 0.5f);
    while (by * (129 - by) / 2 > b) --by;
    while ((by + 1) * (129 - (by + 1)) / 2 <= b) ++by;
    const int bx = by + (b - by * (129 - by) / 2);
    const bool diag  = (by == bx);
    const bool isPos = (bx - by == 32);

    const int rowBase = by * 128;
    const int colBase = bx * 128;

    const int tid  = threadIdx.x;
    const int w    = tid >> 6;      // 0..3
    const int lane = tid & 63;
    const int wr = w >> 1;          // 0..1 -> 64-row strip
    const int wc = w & 1;           // 0..1 -> 64-col strip

    // per-lane fragment base pointers
    const int kOff = (lane >> 4) * 8;
    const u16* aPtr = zn + (size_t)(rowBase + wr * 64 + (lane & 15)) * DIM + kOff;
    const u16* bPtr = zn + (size_t)(colBase + wc * 64 + (lane & 15)) * DIM + kOff;

    f32x4 acc[4][4] = {};

    auto loadAB = [&](short8* a, short8* bf, int u) {
        #pragma unroll
        for (int mi = 0; mi < 4; ++mi)
            a[mi] = *reinterpret_cast<const short8*>(aPtr + (size_t)mi * 16 * DIM + u * 32);
        #pragma unroll
        for (int ni = 0; ni < 4; ++ni)
            bf[ni] = *reinterpret_cast<const short8*>(bPtr + (size_t)ni * 16 * DIM + u * 32);
    };
    auto mmac = [&](const short8* a, const short8* bf) {
        __builtin_amdgcn_s_setprio(1);
        #pragma unroll
        for (int mi = 0; mi < 4; ++mi)
            #pragma unroll
            for (int ni = 0; ni < 4; ++ni)
                acc[mi][ni] = __builtin_amdgcn_mfma_f32_16x16x32_bf16(
                    a[mi], bf[ni], acc[mi][ni], 0, 0, 0);
        __builtin_amdgcn_s_setprio(0);
    };

    // K = 256 = 8 chunks of 32; named reg buffers (static indexing), the
    // full unroll lets the compiler software-pipeline loads across chunks.
    short8 aA[4], bA[4], aB[4], bB[4];
    loadAB(aA, bA, 0);
    #pragma unroll
    for (int u = 0; u < 8; u += 2) {
        if (u + 1 < 8) loadAB(aB, bB, u + 1);
        mmac(aA, bA);
        if (u + 2 < 8) loadAB(aA, bA, u + 2);
        mmac(aB, bB);
    }

    // -------- epilogue: no atomics, unique-slot coalesced stores --------
    // C/D layout: col = lane&15, row = (lane>>4)*4 + v
    float cs[4] = {0.f, 0.f, 0.f, 0.f};
    float* rowSlot = slab + (size_t)(bx * 2 + wc) * NROWS + rowBase + wr * 64;
    #pragma unroll
    for (int mi = 0; mi < 4; ++mi) {
        f32x4 rs = {0.f, 0.f, 0.f, 0.f};
        #pragma unroll
        for (int ni = 0; ni < 4; ++ni)
            #pragma unroll
            for (int v = 0; v < 4; ++v) {
                const int R = wr * 64 + mi * 16 + (lane >> 4) * 4 + v;
                const int C = wc * 64 + ni * 16 + (lane & 15);
                float e = __expf(TEMP_INV * acc[mi][ni][v]);
                if (diag && R == C) e = 0.f;   // exclude self-similarity
                rs[v] += e;
                cs[ni] += e;
            }
        #pragma unroll
        for (int v = 0; v < 4; ++v) {
            float s = rs[v];
            s += __shfl_xor(s, 1);
            s += __shfl_xor(s, 2);
            s += __shfl_xor(s, 4);
            s += __shfl_xor(s, 8);
            rs[v] = s;
        }
        if ((lane & 15) == 0)   // 4 lanes -> one coalesced 64B store
            *reinterpret_cast<f32x4*>(rowSlot + mi * 16 + (lane >> 4) * 4) = rs;
    }
    if (!diag) {
        // symmetric contribution: col sums -> slab[by*2 + wr][colBase + c]
        float* colSlot = slab + (size_t)(by * 2 + wr) * NROWS + colBase + wc * 64;
        #pragma unroll
        for (int ni = 0; ni < 4; ++ni) {
            float c = cs[ni];
            c += __shfl_xor(c, 16);
            c += __shfl_xor(c, 32);
            if (lane < 16)
                colSlot[ni * 16 + lane] = c;
        }
    }
    if (isPos) {
        // tile-diagonal elements are sim(i, i+HALF)
        #pragma unroll
        for (int mi = 0; mi < 4; ++mi)
            #pragma unroll
            for (int ni = 0; ni < 4; ++ni)
                #pragma unroll
                for (int v = 0; v < 4; ++v) {
                    const int R = wr * 64 + mi * 16 + (lane >> 4) * 4 + v;
                    const int C = wc * 64 + ni * 16 + (lane & 15);
                    if (R == C) {
                        const float val = acc[mi][ni][v];
                        pos[rowBase + R] = val;
                        pos[rowBase + R + HALF] = val;
                    }
                }
    }
}

// ---------------- kernel 3: reduce slab rows -> per-block partials ----------
__global__ __launch_bounds__(256) void finalize_k(const float* __restrict__ slab,
                                                  const float* __restrict__ pos,
                                                  float* __restrict__ part) {
    const int row = blockIdx.x * 256 + threadIdx.x;
    float d = 0.f;
    #pragma unroll 8
    for (int j = 0; j < NSLAB; ++j)
        d += slab[(size_t)j * NROWS + row];    // coalesced across threads
    float s = logf(d) - TEMP_INV * pos[row];
    __shared__ float red[256];
    red[threadIdx.x] = s;
    __syncthreads();
    #pragma unroll
    for (int m = 128; m; m >>= 1) {
        if (threadIdx.x < m) red[threadIdx.x] += red[threadIdx.x + m];
        __syncthreads();
    }
    if (threadIdx.x == 0) part[blockIdx.x] = red[0];
}

// ---------------- kernel 4: sum 32 partials (deterministic, no atomics) -----
__global__ __launch_bounds__(64) void sum_k(const float* __restrict__ part,
                                            float* __restrict__ out) {
    float v = (threadIdx.x < 32) ? part[threadIdx.x] : 0.f;
    #pragma unroll
    for (int m = 32; m; m >>= 1) v += __shfl_xor(v, m);
    if (threadIdx.x == 0) out[0] = v * (1.0f / NROWS);
}

extern "C" void kernel_launch(void* const* d_in, const int* in_sizes, int n_in,
                              void* d_out, int out_size, void* d_ws, size_t ws_size,
                              hipStream_t stream) {
    const float* zi = (const float*)d_in[0];
    const float* zj = (const float*)d_in[1];
    float* out = (float*)d_out;

    // workspace: zn bf16 [8192][256] (4 MiB) | slab f32 [128][8192] (4 MiB)
    //            | pos f32 [8192] | part f32 [32]
    u16*   zn   = (u16*)d_ws;
    float* slab = (float*)((char*)d_ws + (size_t)NROWS * DIM * sizeof(u16));
    float* pos  = slab + (size_t)NSLAB * NROWS;
    float* part = pos + NROWS;

    normalize_k<<<NROWS / 4, 256, 0, stream>>>(zi, zj, zn);
    gemm_exp_rowsum<<<NBLK, 256, 0, stream>>>(zn, slab, pos);
    finalize_k<<<NROWS / 256, 256, 0, stream>>>(slab, pos, part);
    sum_k<<<1, 64, 0, stream>>>(part, out);
}

// Round 8
// 48.154 us; speedup vs baseline: 1.7999x; 1.7999x over previous
//
#include <hip/hip_runtime.h>
#include <hip/hip_bf16.h>

typedef __attribute__((ext_vector_type(8))) short short8;
typedef __attribute__((ext_vector_type(4))) float f32x4;
typedef unsigned short u16;
typedef unsigned int u32;

#define NROWS 8192
#define HALF  4096
#define DIM   256
#define TEMP_INV 2.0f   // 1/temperature
#define BK 32
#define NBT 64                        // 8192/128 tiles per side
#define NBLK (NBT * (NBT + 1) / 2)    // 2080 triangular tiles
#define NSLAB 128                     // 64 tiles * 2 wave-halves

#define BARRIER() asm volatile("s_barrier" ::: "memory")
#define WAITV(n)  asm volatile("s_waitcnt vmcnt(" #n ")" ::: "memory")

__device__ __forceinline__ u16 f2bf(float f) {
    union { float f; u32 i; } c; c.f = f;
    u32 lsb = (c.i >> 16) & 1;
    c.i += 0x7fffu + lsb;   // round-to-nearest-even
    return (u16)(c.i >> 16);
}

// ---------------- kernel 1: normalize rows, write bf16 ----------------------
__global__ __launch_bounds__(256) void normalize_k(const float* __restrict__ zi,
                                                   const float* __restrict__ zj,
                                                   u16* __restrict__ zn) {
    const int row  = blockIdx.x * 4 + (threadIdx.x >> 6);
    const int lane = threadIdx.x & 63;
    const float* src = (row < HALF) ? (zi + (size_t)row * DIM)
                                    : (zj + (size_t)(row - HALF) * DIM);
    float4 v = reinterpret_cast<const float4*>(src)[lane];
    float ss = v.x * v.x + v.y * v.y + v.z * v.z + v.w * v.w;
    #pragma unroll
    for (int m = 32; m; m >>= 1) ss += __shfl_xor(ss, m);
    const float inv = 1.0f / fmaxf(sqrtf(ss), 1e-8f);
    ushort4 o;
    o.x = f2bf(v.x * inv); o.y = f2bf(v.y * inv);
    o.z = f2bf(v.z * inv); o.w = f2bf(v.w * inv);
    reinterpret_cast<ushort4*>(zn + (size_t)row * DIM)[lane] = o;
}

// ---------------- kernel 2: triple-buffered triangular GEMM -----------------
// 3 LDS buffers, ONE barrier + ONE counted WAITV per K-step. stage(t+2) is
// issued at the end of step t and required at entry of step t+2 -> prefetch
// cover = a full iteration (2-3x the double-buffer scheme), enough for L2
// latency. Buffer-overwrite hazard guarded by the entry barrier (it sits
// after all waves' compute(t-1)).
__device__ __forceinline__ void gload16(const void* g, void* lds) {
    __builtin_amdgcn_global_load_lds(
        (const __attribute__((address_space(1))) u32*)g,
        (__attribute__((address_space(3))) u32*)lds, 16, 0, 0);
}

__global__ __launch_bounds__(256, 3) void gemm_exp_rowsum(const u16* __restrict__ zn,
                                                          float* __restrict__ slab,
                                                          float* __restrict__ pos) {
    // XCD-aware bijective swizzle (2080 = 8 * 260)
    const int b0 = blockIdx.x;
    const int b  = (b0 & 7) * (NBLK / 8) + (b0 >> 3);
    // Triangular decode: b -> (by, bx), by <= bx < 64
    int by = (int)((129.0f - sqrtf(129.0f * 129.0f - 8.0f * (float)b)) * 0.5f);
    while (by * (129 - by) / 2 > b) --by;
    while ((by + 1) * (129 - (by + 1)) / 2 <= b) ++by;
    const int bx = by + (b - by * (129 - by) / 2);
    const bool diag  = (by == bx);
    const bool isPos = (bx - by == 32);

    const int rowBase = by * 128;
    const int colBase = bx * 128;

    __shared__ u16 As[3][128 * BK];   // 8 KiB per buf
    __shared__ u16 Bs[3][128 * BK];   // total LDS 48 KiB -> 3 blocks/CU

    const int tid  = threadIdx.x;
    const int w    = tid >> 6;      // 0..3
    const int lane = tid & 63;
    const int wr = w >> 1;          // 0..1 -> 64-row strip
    const int wc = w & 1;           // 0..1 -> 64-col strip

    f32x4 acc[4][4] = {};

    // staging: LDS dest linear; source chunk pre-swizzled, key(row)=(row>>1)&3
    const int lr = lane >> 2;
    const int lc = (lane & 3) ^ ((lane >> 3) & 3);

    auto stage = [&](int buf, int kk) {
        #pragma unroll
        for (int s = 0; s < 2; ++s) {
            const int r0 = w * 32 + s * 16;   // wave-uniform
            gload16(zn + (size_t)(rowBase + r0 + lr) * DIM + kk + lc * 8,
                    &As[buf][r0 * BK]);
        }
        #pragma unroll
        for (int s = 0; s < 2; ++s) {
            const int r0 = w * 32 + s * 16;
            gload16(zn + (size_t)(colBase + r0 + lr) * DIM + kk + lc * 8,
                    &Bs[buf][r0 * BK]);
        }
    };

    // ds_read bases: chunk key depends only on lane&15; buf folds to +8192B
    const int chunk = ((lane >> 4) ^ (((lane & 15) >> 1) & 3)) * 16;
    const char* Ab = (const char*)&As[0][0] + (wr * 64 + (lane & 15)) * 64 + chunk;
    const char* Bb = (const char*)&Bs[0][0] + (wc * 64 + (lane & 15)) * 64 + chunk;

    auto compute = [&](int buf) {
        short8 af[4], bfr[4];
        #pragma unroll
        for (int mi = 0; mi < 4; ++mi)
            af[mi] = *reinterpret_cast<const short8*>(Ab + buf * 8192 + mi * 1024);
        #pragma unroll
        for (int ni = 0; ni < 4; ++ni)
            bfr[ni] = *reinterpret_cast<const short8*>(Bb + buf * 8192 + ni * 1024);
        __builtin_amdgcn_s_setprio(1);
        #pragma unroll
        for (int mi = 0; mi < 4; ++mi)
            #pragma unroll
            for (int ni = 0; ni < 4; ++ni)
                acc[mi][ni] = __builtin_amdgcn_mfma_f32_16x16x32_bf16(
                    af[mi], bfr[ni], acc[mi][ni], 0, 0, 0);
        __builtin_amdgcn_s_setprio(0);
    };

    // K = 256 = 8 steps of BK=32; 3-buffer pipeline, 1 barrier/step.
    stage(0, 0);
    stage(1, BK);
    #pragma unroll
    for (int t = 0; t < 8; ++t) {
        if (t < 7) { WAITV(4); }    // oldest stage landed; next 4 in flight
        else       { WAITV(0); }    // final buffer landed
        BARRIER();                  // publish LDS writes; guard buf overwrite
        compute(t % 3);
        if (t < 6) stage((t + 2) % 3, (t + 2) * BK);
    }

    // -------- epilogue: no atomics, unique-slot coalesced stores --------
    // C/D layout: col = lane&15, row = (lane>>4)*4 + v
    float cs[4] = {0.f, 0.f, 0.f, 0.f};
    float* rowSlot = slab + (size_t)(bx * 2 + wc) * NROWS + rowBase + wr * 64;
    #pragma unroll
    for (int mi = 0; mi < 4; ++mi) {
        f32x4 rs = {0.f, 0.f, 0.f, 0.f};
        #pragma unroll
        for (int ni = 0; ni < 4; ++ni)
            #pragma unroll
            for (int v = 0; v < 4; ++v) {
                const int R = wr * 64 + mi * 16 + (lane >> 4) * 4 + v;
                const int C = wc * 64 + ni * 16 + (lane & 15);
                float e = __expf(TEMP_INV * acc[mi][ni][v]);
                if (diag && R == C) e = 0.f;   // exclude self-similarity
                rs[v] += e;
                cs[ni] += e;
            }
        #pragma unroll
        for (int v = 0; v < 4; ++v) {
            float s = rs[v];
            s += __shfl_xor(s, 1);
            s += __shfl_xor(s, 2);
            s += __shfl_xor(s, 4);
            s += __shfl_xor(s, 8);
            rs[v] = s;
        }
        if ((lane & 15) == 0)   // 4 lanes -> one coalesced 64B store
            *reinterpret_cast<f32x4*>(rowSlot + mi * 16 + (lane >> 4) * 4) = rs;
    }
    if (!diag) {
        // symmetric contribution: col sums -> slab[by*2 + wr][colBase + c]
        float* colSlot = slab + (size_t)(by * 2 + wr) * NROWS + colBase + wc * 64;
        #pragma unroll
        for (int ni = 0; ni < 4; ++ni) {
            float c = cs[ni];
            c += __shfl_xor(c, 16);
            c += __shfl_xor(c, 32);
            if (lane < 16)
                colSlot[ni * 16 + lane] = c;
        }
    }
    if (isPos) {
        // tile-diagonal elements are sim(i, i+HALF)
        #pragma unroll
        for (int mi = 0; mi < 4; ++mi)
            #pragma unroll
            for (int ni = 0; ni < 4; ++ni)
                #pragma unroll
                for (int v = 0; v < 4; ++v) {
                    const int R = wr * 64 + mi * 16 + (lane >> 4) * 4 + v;
                    const int C = wc * 64 + ni * 16 + (lane & 15);
                    if (R == C) {
                        const float val = acc[mi][ni][v];
                        pos[rowBase + R] = val;
                        pos[rowBase + R + HALF] = val;
                    }
                }
    }
}

// ---------------- kernel 3: reduce slab rows -> per-block partials ----------
__global__ __launch_bounds__(256) void finalize_k(const float* __restrict__ slab,
                                                  const float* __restrict__ pos,
                                                  float* __restrict__ part) {
    const int row = blockIdx.x * 256 + threadIdx.x;
    float d = 0.f;
    #pragma unroll 8
    for (int j = 0; j < NSLAB; ++j)
        d += slab[(size_t)j * NROWS + row];    // coalesced across threads
    float s = logf(d) - TEMP_INV * pos[row];
    __shared__ float red[256];
    red[threadIdx.x] = s;
    __syncthreads();
    #pragma unroll
    for (int m = 128; m; m >>= 1) {
        if (threadIdx.x < m) red[threadIdx.x] += red[threadIdx.x + m];
        __syncthreads();
    }
    if (threadIdx.x == 0) part[blockIdx.x] = red[0];
}

// ---------------- kernel 4: sum 32 partials (deterministic, no atomics) -----
__global__ __launch_bounds__(64) void sum_k(const float* __restrict__ part,
                                            float* __restrict__ out) {
    float v = (threadIdx.x < 32) ? part[threadIdx.x] : 0.f;
    #pragma unroll
    for (int m = 32; m; m >>= 1) v += __shfl_xor(v, m);
    if (threadIdx.x == 0) out[0] = v * (1.0f / NROWS);
}

extern "C" void kernel_launch(void* const* d_in, const int* in_sizes, int n_in,
                              void* d_out, int out_size, void* d_ws, size_t ws_size,
                              hipStream_t stream) {
    const float* zi = (const float*)d_in[0];
    const float* zj = (const float*)d_in[1];
    float* out = (float*)d_out;

    // workspace: zn bf16 [8192][256] (4 MiB) | slab f32 [128][8192] (4 MiB)
    //            | pos f32 [8192] | part f32 [32]
    u16*   zn   = (u16*)d_ws;
    float* slab = (float*)((char*)d_ws + (size_t)NROWS * DIM * sizeof(u16));
    float* pos  = slab + (size_t)NSLAB * NROWS;
    float* part = pos + NROWS;

    normalize_k<<<NROWS / 4, 256, 0, stream>>>(zi, zj, zn);
    gemm_exp_rowsum<<<NBLK, 256, 0, stream>>>(zn, slab, pos);
    finalize_k<<<NROWS / 256, 256, 0, stream>>>(slab, pos, part);
    sum_k<<<1, 64, 0, stream>>>(part, out);
}